// Round 1
// baseline (2001.316 us; speedup 1.0000x reference)
//
#include <hip/hip_runtime.h>
#include <hip/hip_bf16.h>

// Problem dims
#define B_ 16
#define L_ 2048
#define DF 512
#define H_ 8
#define DH 512
#define U_ 512

// ---------------------------------------------------------------------------
// Kernel A: c[b,h,u] = sum_d hidden[b,h,d]*W2[h,d,u] + b1[h,u] + b2[h,u]
// grid (H_, U_/128), block 128. W2 read exactly once (8 MB).
// ---------------------------------------------------------------------------
__global__ __launch_bounds__(128) void hproj_kernel(
    const float* __restrict__ hidden, const float* __restrict__ W2,
    const float* __restrict__ b1, const float* __restrict__ b2,
    float* __restrict__ c) {
  int h = blockIdx.x;
  int u = blockIdx.y * 128 + threadIdx.x;
  __shared__ float hs[B_][DH];  // 32 KB
  for (int idx = threadIdx.x; idx < B_ * DH; idx += 128) {
    int b = idx >> 9, d = idx & (DH - 1);
    hs[b][d] = hidden[(size_t)(b * H_ + h) * DH + d];
  }
  __syncthreads();
  float acc[B_];
#pragma unroll
  for (int b = 0; b < B_; b++) acc[b] = 0.f;
  const float* w2p = W2 + (size_t)h * DH * U_ + u;
  for (int d = 0; d < DH; d++) {
    float w = w2p[(size_t)d * U_];
#pragma unroll
    for (int b = 0; b < B_; b++) acc[b] += hs[b][d] * w;
  }
  float bias = b1[h * U_ + u] + b2[h * U_ + u];
#pragma unroll
  for (int b = 0; b < B_; b++) c[(size_t)(b * H_ + h) * U_ + u] = acc[b] + bias;
}

// ---------------------------------------------------------------------------
// Kernel B: score[b,h,l] = bV[h] + sum_u V[h,u]*tanh( sum_d F[b,l,d]*W1[h,d,u]
//                                                     + c[b,h,u] )
// Fused GEMM + tanh + V-dot. Tile TL=64 (l) x TU=64 (u), K-tiles of 16.
// 256 threads, 4x4 micro-tile per thread. u-tile loop inside block so the
// U-reduction stays in registers (no atomics, deterministic).
// grid (L_/TL, B_, H_), block 256.
// ---------------------------------------------------------------------------
#define TL 64
#define TU 64
#define TK 16

__global__ __launch_bounds__(256) void score_kernel(
    const float* __restrict__ F, const float* __restrict__ W1,
    const float* __restrict__ C, const float* __restrict__ V,
    const float* __restrict__ bV, float* __restrict__ score) {
  int l0 = blockIdx.x * TL;
  int b = blockIdx.y;
  int h = blockIdx.z;
  int tid = threadIdx.x;
  int tx = tid & 15;   // u-group (4 cols each)
  int ty = tid >> 4;   // l-group (4 rows each)

  __shared__ float Fs[TK][TL + 4];  // +4 pad: conflict-free transposed writes
  __shared__ float Ws[TK][TU];

  const float* Fbase = F + ((size_t)b * L_ + l0) * DF;
  const float* Wbase = W1 + (size_t)h * DF * U_;

  // staging index precompute
  int fl = tid >> 2;         // 0..63 : l row
  int fk = (tid & 3) * 4;    // k offset (float4)
  int wk = tid >> 4;         // 0..15 : k row
  int wu = (tid & 15) * 4;   // u offset (float4)

  float part[4] = {0.f, 0.f, 0.f, 0.f};

  for (int ut = 0; ut < U_ / TU; ++ut) {
    int u0 = ut * TU;
    float acc[4][4] = {};
    for (int kt = 0; kt < DF / TK; ++kt) {
      int k0 = kt * TK;
      __syncthreads();  // previous tile's reads done
      float4 fv = *(const float4*)(Fbase + (size_t)fl * DF + k0 + fk);
      Fs[fk + 0][fl] = fv.x;
      Fs[fk + 1][fl] = fv.y;
      Fs[fk + 2][fl] = fv.z;
      Fs[fk + 3][fl] = fv.w;
      *(float4*)&Ws[wk][wu] =
          *(const float4*)(Wbase + (size_t)(k0 + wk) * U_ + u0 + wu);
      __syncthreads();
#pragma unroll
      for (int kk = 0; kk < TK; ++kk) {
        float4 a = *(const float4*)&Fs[kk][ty * 4];
        float4 w = *(const float4*)&Ws[kk][tx * 4];
        float av[4] = {a.x, a.y, a.z, a.w};
        float wv[4] = {w.x, w.y, w.z, w.w};
#pragma unroll
        for (int i = 0; i < 4; i++)
#pragma unroll
          for (int j = 0; j < 4; j++) acc[i][j] += av[i] * wv[j];
      }
    }
    // epilogue for this u-tile: + c, tanh, * V, reduce over the 4 cols
    float cu[4], vv[4];
#pragma unroll
    for (int j = 0; j < 4; j++) {
      cu[j] = C[((size_t)b * H_ + h) * U_ + u0 + tx * 4 + j];
      vv[j] = V[h * U_ + u0 + tx * 4 + j];
    }
#pragma unroll
    for (int i = 0; i < 4; i++)
#pragma unroll
      for (int j = 0; j < 4; j++)
        part[i] += tanhf(acc[i][j] + cu[j]) * vv[j];
  }

  // reduce across the 16 tx lanes (contiguous within the wave)
#pragma unroll
  for (int i = 0; i < 4; i++) {
    float v = part[i];
#pragma unroll
    for (int off = 1; off < 16; off <<= 1) v += __shfl_xor(v, off, 64);
    part[i] = v;
  }
  if (tx == 0) {
    float bv = bV[h];
#pragma unroll
    for (int i = 0; i < 4; i++)
      score[((size_t)b * H_ + h) * L_ + l0 + ty * 4 + i] = part[i] + bv;
  }
}

// ---------------------------------------------------------------------------
// Kernel C: softmax over L per (b,h); writes attn (ws, [B,H,L]) and the
// attention_weights output ([B,L,H,1] layout). grid (B_*H_), block 256.
// ---------------------------------------------------------------------------
__global__ __launch_bounds__(256) void softmax_kernel(
    const float* __restrict__ score, float* __restrict__ attn,
    float* __restrict__ aw_out) {
  int bh = blockIdx.x;
  int b = bh / H_, h = bh % H_;
  const float* s = score + (size_t)bh * L_;
  __shared__ float red[256];

  float m = -1e30f;
  for (int l = threadIdx.x; l < L_; l += 256) m = fmaxf(m, s[l]);
  red[threadIdx.x] = m;
  __syncthreads();
  for (int st = 128; st > 0; st >>= 1) {
    if (threadIdx.x < st)
      red[threadIdx.x] = fmaxf(red[threadIdx.x], red[threadIdx.x + st]);
    __syncthreads();
  }
  m = red[0];
  __syncthreads();

  float sum = 0.f;
  for (int l = threadIdx.x; l < L_; l += 256) sum += __expf(s[l] - m);
  red[threadIdx.x] = sum;
  __syncthreads();
  for (int st = 128; st > 0; st >>= 1) {
    if (threadIdx.x < st) red[threadIdx.x] += red[threadIdx.x + st];
    __syncthreads();
  }
  float inv = 1.f / red[0];

  for (int l = threadIdx.x; l < L_; l += 256) {
    float a = __expf(s[l] - m) * inv;
    attn[(size_t)bh * L_ + l] = a;
    aw_out[((size_t)b * L_ + l) * H_ + h] = a;
  }
}

// ---------------------------------------------------------------------------
// Kernel D: context[b,h,d] = sum_l attn[b,h,l] * F[b,l,d]
// grid (B_, DF/64), block 256. attn[b,:,:] staged in LDS (64 KB), F read once.
// ---------------------------------------------------------------------------
__global__ __launch_bounds__(256) void context_kernel(
    const float* __restrict__ F, const float* __restrict__ attn,
    float* __restrict__ ctx_out) {
  int b = blockIdx.x;
  int d0 = blockIdx.y * 64;
  int td = threadIdx.x & 63;
  int tl = threadIdx.x >> 6;  // 0..3

  __shared__ float as[H_][L_];  // 64 KB
  for (int idx = threadIdx.x; idx < H_ * L_; idx += 256)
    as[idx >> 11][idx & (L_ - 1)] = attn[(size_t)b * H_ * L_ + idx];
  __syncthreads();

  float acc[H_] = {};
  for (int l = tl; l < L_; l += 4) {
    float f = F[((size_t)b * L_ + l) * DF + d0 + td];
#pragma unroll
    for (int h = 0; h < H_; h++) acc[h] += as[h][l] * f;
  }

  __shared__ float red[4][H_][64];  // 8 KB
#pragma unroll
  for (int h = 0; h < H_; h++) red[tl][h][td] = acc[h];
  __syncthreads();
  if (tl == 0) {
#pragma unroll
    for (int h = 0; h < H_; h++) {
      float v = red[0][h][td] + red[1][h][td] + red[2][h][td] + red[3][h][td];
      ctx_out[((size_t)b * H_ + h) * DF + d0 + td] = v;
    }
  }
}

// ---------------------------------------------------------------------------
extern "C" void kernel_launch(void* const* d_in, const int* in_sizes, int n_in,
                              void* d_out, int out_size, void* d_ws,
                              size_t ws_size, hipStream_t stream) {
  const float* features = (const float*)d_in[0];  // [B,L,Df]
  const float* hidden   = (const float*)d_in[1];  // [B,H,Dh]
  const float* W1       = (const float*)d_in[2];  // [H,Df,U]
  const float* b1       = (const float*)d_in[3];  // [H,U]
  const float* W2       = (const float*)d_in[4];  // [H,Dh,U]
  const float* b2       = (const float*)d_in[5];  // [H,U]
  const float* V        = (const float*)d_in[6];  // [H,U]
  const float* bV       = (const float*)d_in[7];  // [H]

  float* out = (float*)d_out;
  float* ctx_out = out;                    // [B,H,Df] = 65536 floats
  float* aw_out  = out + B_ * H_ * DF;     // [B,L,H,1] = 262144 floats

  // workspace: c (65536) | score (262144) | attn (262144) = 2.25 MB
  float* c_buf = (float*)d_ws;
  float* score = c_buf + (size_t)B_ * H_ * U_;
  float* attn  = score + (size_t)B_ * H_ * L_;

  hproj_kernel<<<dim3(H_, U_ / 128), 128, 0, stream>>>(hidden, W2, b1, b2,
                                                       c_buf);
  score_kernel<<<dim3(L_ / TL, B_, H_), 256, 0, stream>>>(features, W1, c_buf,
                                                          V, bV, score);
  softmax_kernel<<<B_ * H_, 256, 0, stream>>>(score, attn, aw_out);
  context_kernel<<<dim3(B_, DF / 64), 256, 0, stream>>>(features, attn,
                                                        ctx_out);
}

// Round 2
// 423.163 us; speedup vs baseline: 4.7294x; 4.7294x over previous
//
#include <hip/hip_runtime.h>
#include <hip/hip_bf16.h>

// Problem dims
#define B_ 16
#define L_ 2048
#define DF 512
#define H_ 8
#define DH 512
#define U_ 512

typedef unsigned short u16;
typedef __attribute__((ext_vector_type(8))) short bf16x8;
typedef __attribute__((ext_vector_type(4))) float f32x4;

__device__ __forceinline__ u16 f2bf(float x) {
  __hip_bfloat16 h = __float2bfloat16(x);
  u16 u;
  __builtin_memcpy(&u, &h, 2);
  return u;
}

__device__ __forceinline__ void load_lds16(const void* g, void* l) {
  __builtin_amdgcn_global_load_lds(
      (const __attribute__((address_space(1))) void*)g,
      (__attribute__((address_space(3))) void*)l, 16, 0, 0);
}

__device__ __forceinline__ float fast_tanh(float x) {
  float ax = fabsf(x);
  float t = __expf(-2.f * ax);
  float r = __fdividef(1.f - t, 1.f + t);
  return copysignf(r, x);
}

// ---------------------------------------------------------------------------
// Convert features fp32 -> bf16, same layout [B,L,DF]. 4 elems/thread.
// ---------------------------------------------------------------------------
__global__ __launch_bounds__(256) void convert_f_kernel(
    const float* __restrict__ src, u16* __restrict__ dst) {
  size_t i = ((size_t)blockIdx.x * 256 + threadIdx.x) * 4;
  float4 v = *(const float4*)(src + i);
  ushort4 o;
  o.x = f2bf(v.x); o.y = f2bf(v.y); o.z = f2bf(v.z); o.w = f2bf(v.w);
  *(ushort4*)(dst + i) = o;
}

// ---------------------------------------------------------------------------
// Transpose-convert W1 [H,DF(d),U(u)] fp32 -> W1T [H,U,DF] bf16 (k-contig).
// grid (DF/32, U/32, H), block 256, 32x32 LDS tile.
// ---------------------------------------------------------------------------
__global__ __launch_bounds__(256) void convert_w1_kernel(
    const float* __restrict__ W1, u16* __restrict__ W1T) {
  __shared__ float t[32][33];
  int h = blockIdx.z;
  int d0 = blockIdx.x * 32, u0 = blockIdx.y * 32;
  const float* src = W1 + (size_t)h * DF * U_;
  u16* dst = W1T + (size_t)h * U_ * DF;
#pragma unroll
  for (int i = 0; i < 4; ++i) {
    int idx = threadIdx.x + i * 256;
    int r = idx >> 5, c = idx & 31;
    t[r][c] = src[(size_t)(d0 + r) * U_ + u0 + c];
  }
  __syncthreads();
#pragma unroll
  for (int i = 0; i < 4; ++i) {
    int idx = threadIdx.x + i * 256;
    int r = idx >> 5, c = idx & 31;  // r: u index, c: d index
    dst[(size_t)(u0 + r) * DF + d0 + c] = f2bf(t[c][r]);
  }
}

// ---------------------------------------------------------------------------
// Kernel A: c[b,h,u] = sum_d hidden[b,h,d]*W2[h,d,u] + b1[h,u] + b2[h,u]
// ---------------------------------------------------------------------------
__global__ __launch_bounds__(128) void hproj_kernel(
    const float* __restrict__ hidden, const float* __restrict__ W2,
    const float* __restrict__ b1, const float* __restrict__ b2,
    float* __restrict__ c) {
  int h = blockIdx.x;
  int u = blockIdx.y * 128 + threadIdx.x;
  __shared__ float hs[B_][DH];
  for (int idx = threadIdx.x; idx < B_ * DH; idx += 128) {
    int b = idx >> 9, d = idx & (DH - 1);
    hs[b][d] = hidden[(size_t)(b * H_ + h) * DH + d];
  }
  __syncthreads();
  float acc[B_];
#pragma unroll
  for (int b = 0; b < B_; b++) acc[b] = 0.f;
  const float* w2p = W2 + (size_t)h * DH * U_ + u;
  for (int d = 0; d < DH; d++) {
    float w = w2p[(size_t)d * U_];
#pragma unroll
    for (int b = 0; b < B_; b++) acc[b] += hs[b][d] * w;
  }
  float bias = b1[h * U_ + u] + b2[h * U_ + u];
#pragma unroll
  for (int b = 0; b < B_; b++) c[(size_t)(b * H_ + h) * U_ + u] = acc[b] + bias;
}

// ---------------------------------------------------------------------------
// Kernel B (MFMA): score[b,h,l] = bV[h]
//        + sum_u V[h,u]*tanh( sum_d F[b,l,d]*W1[h,d,u] + c[b,h,u] )
// 128(M l) x 128(N u-chunk) tile, 4 waves in 2x2, each owns 64x64 quadrant.
// N-chunk loop covers U=512; partials stay in registers; BK=32 double-buffer
// staged via global_load_lds. grid (L/128, B, H), block 256.
// ---------------------------------------------------------------------------
__global__ __launch_bounds__(256, 2) void score_kernel(
    const u16* __restrict__ Abf, const u16* __restrict__ W1T,
    const float* __restrict__ C, const float* __restrict__ V,
    const float* __restrict__ bV, float* __restrict__ score) {
  int l0 = blockIdx.x * 128;
  int b = blockIdx.y, h = blockIdx.z;
  int tid = threadIdx.x;
  int lane = tid & 63, wid = tid >> 6;
  int wr = wid >> 1, wc = wid & 1;
  int rl = lane & 15;
  int khalf = (lane >> 4) << 3;  // 8*quad (bf16 elements)

  __shared__ u16 As[2][128 * 32];
  __shared__ u16 Bs[2][128 * 32];
  __shared__ float redsm[2][128];

  const u16* Fb = Abf + (size_t)b * L_ * DF;
  const u16* Wh = W1T + (size_t)h * U_ * DF;
  const float* Cb = C + (size_t)(b * H_ + h) * U_;
  const float* Vh = V + (size_t)h * U_;

  float part[16];
#pragma unroll
  for (int p = 0; p < 16; ++p) part[p] = 0.f;

  for (int nc = 0; nc < 4; ++nc) {
    int N0 = nc * 128;
    f32x4 acc[4][4];
#pragma unroll
    for (int m = 0; m < 4; ++m)
#pragma unroll
      for (int n = 0; n < 4; ++n)
#pragma unroll
        for (int j = 0; j < 4; ++j) acc[m][n][j] = 0.f;

    // stage K-step 0 of this n-chunk
#pragma unroll
    for (int i = 0; i < 2; ++i) {
      int flat = (i * 256 + tid) * 8;
      int row = flat >> 5, kk = flat & 31;
      load_lds16(Fb + ((size_t)(l0 + row) << 9) + kk, &As[0][flat]);
      load_lds16(Wh + ((size_t)(N0 + row) << 9) + kk, &Bs[0][flat]);
    }
    int cur = 0;
    for (int kt = 0; kt < 16; ++kt) {
      __syncthreads();  // drains staging of buf[cur]
      if (kt < 15) {
        int k0 = (kt + 1) * 32;
#pragma unroll
        for (int i = 0; i < 2; ++i) {
          int flat = (i * 256 + tid) * 8;
          int row = flat >> 5, kk = flat & 31;
          load_lds16(Fb + ((size_t)(l0 + row) << 9) + k0 + kk,
                     &As[cur ^ 1][flat]);
          load_lds16(Wh + ((size_t)(N0 + row) << 9) + k0 + kk,
                     &Bs[cur ^ 1][flat]);
        }
      }
      bf16x8 af[4], bfr[4];
#pragma unroll
      for (int m = 0; m < 4; ++m)
        af[m] = *(const bf16x8*)&As[cur][(wr * 64 + m * 16 + rl) * 32 + khalf];
#pragma unroll
      for (int n = 0; n < 4; ++n)
        bfr[n] = *(const bf16x8*)&Bs[cur][(wc * 64 + n * 16 + rl) * 32 + khalf];
#pragma unroll
      for (int m = 0; m < 4; ++m)
#pragma unroll
        for (int n = 0; n < 4; ++n)
          acc[m][n] = __builtin_amdgcn_mfma_f32_16x16x32_bf16(
              af[m], bfr[n], acc[m][n], 0, 0, 0);
      cur ^= 1;
    }
    // epilogue for this n-chunk: +c, tanh, *V, accumulate per-row partials
#pragma unroll
    for (int n = 0; n < 4; ++n) {
      int col = N0 + wc * 64 + n * 16 + rl;
      float cu = Cb[col];
      float vv = Vh[col];
#pragma unroll
      for (int m = 0; m < 4; ++m)
#pragma unroll
        for (int j = 0; j < 4; ++j)
          part[m * 4 + j] += fast_tanh(acc[m][n][j] + cu) * vv;
    }
  }

  // reduce over the 16 cols held per 16-lane group
#pragma unroll
  for (int p = 0; p < 16; ++p) {
    float v = part[p];
    v += __shfl_xor(v, 1, 64);
    v += __shfl_xor(v, 2, 64);
    v += __shfl_xor(v, 4, 64);
    v += __shfl_xor(v, 8, 64);
    part[p] = v;
  }
  __syncthreads();
  if (rl == 0) {
    int rq = lane >> 4;
#pragma unroll
    for (int m = 0; m < 4; ++m)
#pragma unroll
      for (int j = 0; j < 4; ++j)
        redsm[wc][wr * 64 + m * 16 + rq * 4 + j] = part[m * 4 + j];
  }
  __syncthreads();
  if (tid < 128) {
    float s = redsm[0][tid] + redsm[1][tid] + bV[h];
    score[(size_t)(b * H_ + h) * L_ + l0 + tid] = s;
  }
}

// ---------------------------------------------------------------------------
// Kernel C: softmax over L per (b,h); writes attn (ws) and aw_out [B,L,H,1].
// ---------------------------------------------------------------------------
__global__ __launch_bounds__(256) void softmax_kernel(
    const float* __restrict__ score, float* __restrict__ attn,
    float* __restrict__ aw_out) {
  int bh = blockIdx.x;
  int b = bh / H_, h = bh % H_;
  const float* s = score + (size_t)bh * L_;
  __shared__ float red[256];

  float m = -1e30f;
  for (int l = threadIdx.x; l < L_; l += 256) m = fmaxf(m, s[l]);
  red[threadIdx.x] = m;
  __syncthreads();
  for (int st = 128; st > 0; st >>= 1) {
    if (threadIdx.x < st)
      red[threadIdx.x] = fmaxf(red[threadIdx.x], red[threadIdx.x + st]);
    __syncthreads();
  }
  m = red[0];
  __syncthreads();

  float sum = 0.f;
  for (int l = threadIdx.x; l < L_; l += 256) sum += __expf(s[l] - m);
  red[threadIdx.x] = sum;
  __syncthreads();
  for (int st = 128; st > 0; st >>= 1) {
    if (threadIdx.x < st) red[threadIdx.x] += red[threadIdx.x + st];
    __syncthreads();
  }
  float inv = 1.f / red[0];

  for (int l = threadIdx.x; l < L_; l += 256) {
    float a = __expf(s[l] - m) * inv;
    attn[(size_t)bh * L_ + l] = a;
    aw_out[((size_t)b * L_ + l) * H_ + h] = a;
  }
}

// ---------------------------------------------------------------------------
// Kernel D: context[b,h,d] = sum_l attn[b,h,l] * F[b,l,d]
// ---------------------------------------------------------------------------
__global__ __launch_bounds__(256) void context_kernel(
    const float* __restrict__ F, const float* __restrict__ attn,
    float* __restrict__ ctx_out) {
  int b = blockIdx.x;
  int d0 = blockIdx.y * 64;
  int td = threadIdx.x & 63;
  int tl = threadIdx.x >> 6;

  __shared__ float as[H_][L_];  // 64 KB
  for (int idx = threadIdx.x; idx < H_ * L_; idx += 256)
    as[idx >> 11][idx & (L_ - 1)] = attn[(size_t)b * H_ * L_ + idx];
  __syncthreads();

  float acc[H_] = {};
  for (int l = tl; l < L_; l += 4) {
    float f = F[((size_t)b * L_ + l) * DF + d0 + td];
#pragma unroll
    for (int h = 0; h < H_; h++) acc[h] += as[h][l] * f;
  }

  __shared__ float red[4][H_][64];
#pragma unroll
  for (int h = 0; h < H_; h++) red[tl][h][td] = acc[h];
  __syncthreads();
  if (tl == 0) {
#pragma unroll
    for (int h = 0; h < H_; h++) {
      float v = red[0][h][td] + red[1][h][td] + red[2][h][td] + red[3][h][td];
      ctx_out[((size_t)b * H_ + h) * DF + d0 + td] = v;
    }
  }
}

// ---------------------------------------------------------------------------
extern "C" void kernel_launch(void* const* d_in, const int* in_sizes, int n_in,
                              void* d_out, int out_size, void* d_ws,
                              size_t ws_size, hipStream_t stream) {
  const float* features = (const float*)d_in[0];  // [B,L,Df]
  const float* hidden   = (const float*)d_in[1];  // [B,H,Dh]
  const float* W1       = (const float*)d_in[2];  // [H,Df,U]
  const float* b1       = (const float*)d_in[3];  // [H,U]
  const float* W2       = (const float*)d_in[4];  // [H,Dh,U]
  const float* b2       = (const float*)d_in[5];  // [H,U]
  const float* V        = (const float*)d_in[6];  // [H,U]
  const float* bV       = (const float*)d_in[7];  // [H]

  float* out = (float*)d_out;
  float* ctx_out = out;                 // [B,H,Df]
  float* aw_out  = out + B_ * H_ * DF;  // [B,L,H,1]

  // workspace layout (floats): c | score | attn, then bf16: Abf | W1T
  float* c_buf = (float*)d_ws;
  float* score = c_buf + (size_t)B_ * H_ * U_;
  float* attn  = score + (size_t)B_ * H_ * L_;
  u16* Abf = (u16*)(attn + (size_t)B_ * H_ * L_);
  u16* W1T = Abf + (size_t)B_ * L_ * DF;
  // total ws use: ~2.4 MB fp32 + 33.6 MB + 4.2 MB bf16 ≈ 40 MB

  convert_f_kernel<<<(B_ * L_ * DF) / (256 * 4), 256, 0, stream>>>(features,
                                                                   Abf);
  convert_w1_kernel<<<dim3(DF / 32, U_ / 32, H_), 256, 0, stream>>>(W1, W1T);
  hproj_kernel<<<dim3(H_, U_ / 128), 128, 0, stream>>>(hidden, W2, b1, b2,
                                                       c_buf);
  score_kernel<<<dim3(L_ / 128, B_, H_), 256, 0, stream>>>(Abf, W1T, c_buf, V,
                                                           bV, score);
  softmax_kernel<<<B_ * H_, 256, 0, stream>>>(score, attn, aw_out);
  context_kernel<<<dim3(B_, DF / 64), 256, 0, stream>>>(features, attn,
                                                        ctx_out);
}

// Round 3
// 347.250 us; speedup vs baseline: 5.7633x; 1.2186x over previous
//
#include <hip/hip_runtime.h>
#include <hip/hip_bf16.h>

// Problem dims
#define B_ 16
#define L_ 2048
#define DF 512
#define H_ 8
#define DH 512
#define U_ 512

typedef unsigned short u16;
typedef __attribute__((ext_vector_type(8))) short bf16x8;
typedef __attribute__((ext_vector_type(4))) float f32x4;

__device__ __forceinline__ u16 f2bf(float x) {
  __hip_bfloat16 h = __float2bfloat16(x);
  u16 u;
  __builtin_memcpy(&u, &h, 2);
  return u;
}

__device__ __forceinline__ void load_lds16(const void* g, void* l) {
  __builtin_amdgcn_global_load_lds(
      (const __attribute__((address_space(1))) void*)g,
      (__attribute__((address_space(3))) void*)l, 16, 0, 0);
}

__device__ __forceinline__ float fast_tanh(float x) {
  float ax = fabsf(x);
  float t = __expf(-2.f * ax);
  float r = __fdividef(1.f - t, 1.f + t);
  return copysignf(r, x);
}

// ---------------------------------------------------------------------------
// Convert features fp32 -> bf16, same layout [B,L,DF]. 4 elems/thread.
// ---------------------------------------------------------------------------
__global__ __launch_bounds__(256) void convert_f_kernel(
    const float* __restrict__ src, u16* __restrict__ dst) {
  size_t i = ((size_t)blockIdx.x * 256 + threadIdx.x) * 4;
  float4 v = *(const float4*)(src + i);
  ushort4 o;
  o.x = f2bf(v.x); o.y = f2bf(v.y); o.z = f2bf(v.z); o.w = f2bf(v.w);
  *(ushort4*)(dst + i) = o;
}

// ---------------------------------------------------------------------------
// Transpose-convert W1 [H,DF(d),U(u)] fp32 -> W1T [H,U,DF] bf16 (k-contig).
// ---------------------------------------------------------------------------
__global__ __launch_bounds__(256) void convert_w1_kernel(
    const float* __restrict__ W1, u16* __restrict__ W1T) {
  __shared__ float t[32][33];
  int h = blockIdx.z;
  int d0 = blockIdx.x * 32, u0 = blockIdx.y * 32;
  const float* src = W1 + (size_t)h * DF * U_;
  u16* dst = W1T + (size_t)h * U_ * DF;
#pragma unroll
  for (int i = 0; i < 4; ++i) {
    int idx = threadIdx.x + i * 256;
    int r = idx >> 5, c = idx & 31;
    t[r][c] = src[(size_t)(d0 + r) * U_ + u0 + c];
  }
  __syncthreads();
#pragma unroll
  for (int i = 0; i < 4; ++i) {
    int idx = threadIdx.x + i * 256;
    int r = idx >> 5, c = idx & 31;  // r: u index, c: d index
    dst[(size_t)(u0 + r) * DF + d0 + c] = f2bf(t[c][r]);
  }
}

// ---------------------------------------------------------------------------
// Kernel A (split-d): partial[z,b,h,u] = sum_{d in chunk z} hidden*W2
// grid (H, U/128, 8), block 128. Then combine adds 8 partials + biases.
// ---------------------------------------------------------------------------
__global__ __launch_bounds__(128) void hproj_part_kernel(
    const float* __restrict__ hidden, const float* __restrict__ W2,
    float* __restrict__ partial) {
  int h = blockIdx.x;
  int u = blockIdx.y * 128 + threadIdx.x;
  int d0 = blockIdx.z * 64;
  __shared__ float hs[B_][64];
  for (int idx = threadIdx.x; idx < B_ * 64; idx += 128) {
    int b = idx >> 6, d = idx & 63;
    hs[b][d] = hidden[(size_t)(b * H_ + h) * DH + d0 + d];
  }
  __syncthreads();
  float acc[B_];
#pragma unroll
  for (int b = 0; b < B_; b++) acc[b] = 0.f;
  const float* w2p = W2 + ((size_t)h * DH + d0) * U_ + u;
  for (int d = 0; d < 64; d++) {
    float w = w2p[(size_t)d * U_];
#pragma unroll
    for (int b = 0; b < B_; b++) acc[b] += hs[b][d] * w;
  }
#pragma unroll
  for (int b = 0; b < B_; b++)
    partial[(((size_t)blockIdx.z * B_ + b) * H_ + h) * U_ + u] = acc[b];
}

__global__ __launch_bounds__(256) void hproj_combine_kernel(
    const float* __restrict__ partial, const float* __restrict__ b1,
    const float* __restrict__ b2, float* __restrict__ c) {
  int i = blockIdx.x * 256 + threadIdx.x;  // over B*H*U
  int hu = i & (H_ * U_ - 1);
  float s = b1[hu] + b2[hu];
#pragma unroll
  for (int z = 0; z < 8; z++) s += partial[(size_t)z * B_ * H_ * U_ + i];
  c[i] = s;
}

// ---------------------------------------------------------------------------
// Kernel B (MFMA): score[b,h,l] = bV[h]
//        + sum_u V[h,u]*tanh( sum_d F[b,l,d]*W1[h,d,u] + c[b,h,u] )
// 128(M l) x 128(N u-chunk) tile, BK=64, double-buffered LDS via
// global_load_lds with source-side XOR swizzle (chunk ^= row&7 at 16B
// granularity) so ds_read_b128 is bank-conflict-free. 4 waves 2x2, each a
// 64x64 quadrant. nc loop covers U=512 with partials in registers.
// grid (L/128, B, H), block 256.
// ---------------------------------------------------------------------------
#define BK 64

__global__ __launch_bounds__(256, 2) void score_kernel(
    const u16* __restrict__ Abf, const u16* __restrict__ W1T,
    const float* __restrict__ C, const float* __restrict__ V,
    const float* __restrict__ bV, float* __restrict__ score) {
  int l0 = blockIdx.x * 128;
  int b = blockIdx.y, h = blockIdx.z;
  int tid = threadIdx.x;
  int lane = tid & 63, wid = tid >> 6;
  int wr = wid >> 1, wc = wid & 1;
  int rl = lane & 15;
  int khalf = (lane >> 4) << 3;  // bf16 elem offset of this quad's 16B

  __shared__ u16 As[2][128 * BK];  // 16 KB each -> 64 KB total
  __shared__ u16 Bs[2][128 * BK];
  __shared__ float redsm[2][128];

  const u16* Fb = Abf + (size_t)b * L_ * DF;
  const u16* Wh = W1T + (size_t)h * U_ * DF;
  const float* Cb = C + (size_t)(b * H_ + h) * U_;
  const float* Vh = V + (size_t)h * U_;

  // staging constants: 1024 16B-chunks per matrix per K-step, 4 per thread
  // linear LDS chunk idx -> (row = idx>>3, ch = idx&7); logical k-chunk is
  // ch ^ (row&7)  (involution; same XOR applied on the read side)
  float part[16];
#pragma unroll
  for (int p = 0; p < 16; ++p) part[p] = 0.f;

#define STAGE(buf, kbase)                                                  \
  {                                                                        \
    _Pragma("unroll") for (int i_ = 0; i_ < 4; ++i_) {                     \
      int idx_ = i_ * 256 + tid;                                           \
      int row_ = idx_ >> 3;                                                \
      int ke_ = ((idx_ & 7) ^ (row_ & 7)) << 3;                            \
      load_lds16(Fb + (((size_t)(l0 + row_)) << 9) + (kbase) + ke_,        \
                 &As[buf][idx_ * 8]);                                      \
      load_lds16(Wh + (((size_t)(N0 + row_)) << 9) + (kbase) + ke_,        \
                 &Bs[buf][idx_ * 8]);                                      \
    }                                                                      \
  }

  for (int nc = 0; nc < 4; ++nc) {
    int N0 = nc * 128;
    f32x4 acc[4][4];
#pragma unroll
    for (int m = 0; m < 4; ++m)
#pragma unroll
      for (int n = 0; n < 4; ++n)
#pragma unroll
        for (int j = 0; j < 4; ++j) acc[m][n][j] = 0.f;

    STAGE(0, 0);
    int cur = 0;
    for (int kt = 0; kt < 8; ++kt) {
      __syncthreads();  // drains staging of buf[cur] + prior reads
      if (kt < 7) STAGE(cur ^ 1, (kt + 1) * BK);
#pragma unroll
      for (int s = 0; s < 2; ++s) {
        bf16x8 af[4], bfr[4];
#pragma unroll
        for (int m = 0; m < 4; ++m) {
          int rA = wr * 64 + m * 16 + rl;
          af[m] = *(const bf16x8*)&As[cur][(rA << 6) +
                                           ((s * 32 + khalf) ^ ((rA & 7) << 3))];
        }
#pragma unroll
        for (int n = 0; n < 4; ++n) {
          int rB = wc * 64 + n * 16 + rl;
          bfr[n] = *(const bf16x8*)&Bs[cur][(rB << 6) +
                                            ((s * 32 + khalf) ^ ((rB & 7) << 3))];
        }
#pragma unroll
        for (int m = 0; m < 4; ++m)
#pragma unroll
          for (int n = 0; n < 4; ++n)
            acc[m][n] = __builtin_amdgcn_mfma_f32_16x16x32_bf16(
                af[m], bfr[n], acc[m][n], 0, 0, 0);
      }
      cur ^= 1;
    }
    // epilogue for this n-chunk: +c, tanh, *V, accumulate per-row partials
#pragma unroll
    for (int n = 0; n < 4; ++n) {
      int col = N0 + wc * 64 + n * 16 + rl;
      float cu = Cb[col];
      float vv = Vh[col];
#pragma unroll
      for (int m = 0; m < 4; ++m)
#pragma unroll
        for (int j = 0; j < 4; ++j)
          part[m * 4 + j] += fast_tanh(acc[m][n][j] + cu) * vv;
    }
  }
#undef STAGE

  // reduce over the 16 cols held per 16-lane group
#pragma unroll
  for (int p = 0; p < 16; ++p) {
    float v = part[p];
    v += __shfl_xor(v, 1, 64);
    v += __shfl_xor(v, 2, 64);
    v += __shfl_xor(v, 4, 64);
    v += __shfl_xor(v, 8, 64);
    part[p] = v;
  }
  __syncthreads();
  if (rl == 0) {
    int rq = lane >> 4;
#pragma unroll
    for (int m = 0; m < 4; ++m)
#pragma unroll
      for (int j = 0; j < 4; ++j)
        redsm[wc][wr * 64 + m * 16 + rq * 4 + j] = part[m * 4 + j];
  }
  __syncthreads();
  if (tid < 128) {
    float s = redsm[0][tid] + redsm[1][tid] + bV[h];
    score[(size_t)(b * H_ + h) * L_ + l0 + tid] = s;
  }
}

// ---------------------------------------------------------------------------
// Kernel C: softmax over L per (b,h); writes attn (ws) and aw_out [B,L,H,1].
// ---------------------------------------------------------------------------
__global__ __launch_bounds__(256) void softmax_kernel(
    const float* __restrict__ score, float* __restrict__ attn,
    float* __restrict__ aw_out) {
  int bh = blockIdx.x;
  int b = bh / H_, h = bh % H_;
  const float* s = score + (size_t)bh * L_;
  __shared__ float red[256];

  float m = -1e30f;
  for (int l = threadIdx.x; l < L_; l += 256) m = fmaxf(m, s[l]);
  red[threadIdx.x] = m;
  __syncthreads();
  for (int st = 128; st > 0; st >>= 1) {
    if (threadIdx.x < st)
      red[threadIdx.x] = fmaxf(red[threadIdx.x], red[threadIdx.x + st]);
    __syncthreads();
  }
  m = red[0];
  __syncthreads();

  float sum = 0.f;
  for (int l = threadIdx.x; l < L_; l += 256) sum += __expf(s[l] - m);
  red[threadIdx.x] = sum;
  __syncthreads();
  for (int st = 128; st > 0; st >>= 1) {
    if (threadIdx.x < st) red[threadIdx.x] += red[threadIdx.x + st];
    __syncthreads();
  }
  float inv = 1.f / red[0];

  for (int l = threadIdx.x; l < L_; l += 256) {
    float a = __expf(s[l] - m) * inv;
    attn[(size_t)bh * L_ + l] = a;
    aw_out[((size_t)b * L_ + l) * H_ + h] = a;
  }
}

// ---------------------------------------------------------------------------
// Kernel D: context[b,h,d] = sum_l attn[b,h,l] * F[b,l,d]
// ---------------------------------------------------------------------------
__global__ __launch_bounds__(256) void context_kernel(
    const float* __restrict__ F, const float* __restrict__ attn,
    float* __restrict__ ctx_out) {
  int b = blockIdx.x;
  int d0 = blockIdx.y * 64;
  int td = threadIdx.x & 63;
  int tl = threadIdx.x >> 6;

  __shared__ float as[H_][L_];  // 64 KB
  for (int idx = threadIdx.x; idx < H_ * L_; idx += 256)
    as[idx >> 11][idx & (L_ - 1)] = attn[(size_t)b * H_ * L_ + idx];
  __syncthreads();

  float acc[H_] = {};
  for (int l = tl; l < L_; l += 4) {
    float f = F[((size_t)b * L_ + l) * DF + d0 + td];
#pragma unroll
    for (int h = 0; h < H_; h++) acc[h] += as[h][l] * f;
  }

  __shared__ float red[4][H_][64];
#pragma unroll
  for (int h = 0; h < H_; h++) red[tl][h][td] = acc[h];
  __syncthreads();
  if (tl == 0) {
#pragma unroll
    for (int h = 0; h < H_; h++) {
      float v = red[0][h][td] + red[1][h][td] + red[2][h][td] + red[3][h][td];
      ctx_out[((size_t)b * H_ + h) * DF + d0 + td] = v;
    }
  }
}

// ---------------------------------------------------------------------------
extern "C" void kernel_launch(void* const* d_in, const int* in_sizes, int n_in,
                              void* d_out, int out_size, void* d_ws,
                              size_t ws_size, hipStream_t stream) {
  const float* features = (const float*)d_in[0];  // [B,L,Df]
  const float* hidden   = (const float*)d_in[1];  // [B,H,Dh]
  const float* W1       = (const float*)d_in[2];  // [H,Df,U]
  const float* b1       = (const float*)d_in[3];  // [H,U]
  const float* W2       = (const float*)d_in[4];  // [H,Dh,U]
  const float* b2       = (const float*)d_in[5];  // [H,U]
  const float* V        = (const float*)d_in[6];  // [H,U]
  const float* bV       = (const float*)d_in[7];  // [H]

  float* out = (float*)d_out;
  float* ctx_out = out;                 // [B,H,Df]
  float* aw_out  = out + B_ * H_ * DF;  // [B,L,H,1]

  // workspace layout (floats): c | score | attn, then bf16: Abf | W1T.
  // hproj partials (8*B*H*U = 524288 floats) alias score+attn (also 524288):
  // they are fully consumed by hproj_combine before score is written.
  float* c_buf = (float*)d_ws;
  float* score = c_buf + (size_t)B_ * H_ * U_;
  float* attn  = score + (size_t)B_ * H_ * L_;
  float* partial = score;  // alias (see above)
  u16* Abf = (u16*)(attn + (size_t)B_ * H_ * L_);
  u16* W1T = Abf + (size_t)B_ * L_ * DF;

  convert_f_kernel<<<(B_ * L_ * DF) / (256 * 4), 256, 0, stream>>>(features,
                                                                   Abf);
  convert_w1_kernel<<<dim3(DF / 32, U_ / 32, H_), 256, 0, stream>>>(W1, W1T);
  hproj_part_kernel<<<dim3(H_, U_ / 128, 8), 128, 0, stream>>>(hidden, W2,
                                                               partial);
  hproj_combine_kernel<<<(B_ * H_ * U_) / 256, 256, 0, stream>>>(partial, b1,
                                                                 b2, c_buf);
  score_kernel<<<dim3(L_ / 128, B_, H_), 256, 0, stream>>>(Abf, W1T, c_buf, V,
                                                           bV, score);
  softmax_kernel<<<B_ * H_, 256, 0, stream>>>(score, attn, aw_out);
  context_kernel<<<dim3(B_, DF / 64), 256, 0, stream>>>(features, attn,
                                                        ctx_out);
}

// Round 4
// 330.256 us; speedup vs baseline: 6.0599x; 1.0515x over previous
//
#include <hip/hip_runtime.h>
#include <hip/hip_bf16.h>

// Problem dims
#define B_ 16
#define L_ 2048
#define DF 512
#define H_ 8
#define DH 512
#define U_ 512

typedef unsigned short u16;
typedef __attribute__((ext_vector_type(8))) short bf16x8;
typedef __attribute__((ext_vector_type(4))) float f32x4;

__device__ __forceinline__ u16 f2bf(float x) {
  __hip_bfloat16 h = __float2bfloat16(x);
  u16 u;
  __builtin_memcpy(&u, &h, 2);
  return u;
}

__device__ __forceinline__ void load_lds16(const void* g, void* l) {
  __builtin_amdgcn_global_load_lds(
      (const __attribute__((address_space(1))) void*)g,
      (__attribute__((address_space(3))) void*)l, 16, 0, 0);
}

// tanh(x) = 1 - 2/(1+e^{2x}); exact at +-inf, ~1e-6 abs err. 6 VALU inst.
__device__ __forceinline__ float fast_tanh2(float x) {
  float e = __expf(2.f * x);
  return 1.f - __fdividef(2.f, e + 1.f);
}

// ---------------------------------------------------------------------------
// Merged conversion kernel:
//  blocks [0, 16384): features fp32 -> bf16 [B,L,DF], 4 elems/thread
//  blocks [16384, 18432): W1 [H,DF,U] -> W1T [H,U,DF] bf16 (32x32 transpose)
// ---------------------------------------------------------------------------
__global__ __launch_bounds__(256) void convert_kernel(
    const float* __restrict__ F, u16* __restrict__ Abf,
    const float* __restrict__ W1, u16* __restrict__ W1T) {
  __shared__ float t[32][33];
  if (blockIdx.x < 16384) {
    size_t i = ((size_t)blockIdx.x * 256 + threadIdx.x) * 4;
    float4 v = *(const float4*)(F + i);
    ushort4 o;
    o.x = f2bf(v.x); o.y = f2bf(v.y); o.z = f2bf(v.z); o.w = f2bf(v.w);
    *(ushort4*)(Abf + i) = o;
  } else {
    int bid = blockIdx.x - 16384;
    int d0 = (bid & 15) * 32, u0 = ((bid >> 4) & 15) * 32, h = bid >> 8;
    const float* src = W1 + (size_t)h * DF * U_;
    u16* dst = W1T + (size_t)h * U_ * DF;
#pragma unroll
    for (int i = 0; i < 4; ++i) {
      int idx = threadIdx.x + i * 256;
      int r = idx >> 5, c = idx & 31;
      t[r][c] = src[(size_t)(d0 + r) * U_ + u0 + c];
    }
    __syncthreads();
#pragma unroll
    for (int i = 0; i < 4; ++i) {
      int idx = threadIdx.x + i * 256;
      int r = idx >> 5, c = idx & 31;  // r: u index, c: d index
      dst[(size_t)(u0 + r) * DF + d0 + c] = f2bf(t[c][r]);
    }
  }
}

// ---------------------------------------------------------------------------
// hproj split-d: partial[z,b,h,u] = sum_{d in chunk z} hidden*W2
// ---------------------------------------------------------------------------
__global__ __launch_bounds__(128) void hproj_part_kernel(
    const float* __restrict__ hidden, const float* __restrict__ W2,
    float* __restrict__ partial) {
  int h = blockIdx.x;
  int u = blockIdx.y * 128 + threadIdx.x;
  int d0 = blockIdx.z * 64;
  __shared__ float hs[B_][64];
  for (int idx = threadIdx.x; idx < B_ * 64; idx += 128) {
    int b = idx >> 6, d = idx & 63;
    hs[b][d] = hidden[(size_t)(b * H_ + h) * DH + d0 + d];
  }
  __syncthreads();
  float acc[B_];
#pragma unroll
  for (int b = 0; b < B_; b++) acc[b] = 0.f;
  const float* w2p = W2 + ((size_t)h * DH + d0) * U_ + u;
  for (int d = 0; d < 64; d++) {
    float w = w2p[(size_t)d * U_];
#pragma unroll
    for (int b = 0; b < B_; b++) acc[b] += hs[b][d] * w;
  }
#pragma unroll
  for (int b = 0; b < B_; b++)
    partial[(((size_t)blockIdx.z * B_ + b) * H_ + h) * U_ + u] = acc[b];
}

__global__ __launch_bounds__(256) void hproj_combine_kernel(
    const float* __restrict__ partial, const float* __restrict__ b1,
    const float* __restrict__ b2, float* __restrict__ c) {
  int i = blockIdx.x * 256 + threadIdx.x;  // over B*H*U
  int hu = i & (H_ * U_ - 1);
  float s = b1[hu] + b2[hu];
#pragma unroll
  for (int z = 0; z < 8; z++) s += partial[(size_t)z * B_ * H_ * U_ + i];
  c[i] = s;
}

// ---------------------------------------------------------------------------
// score kernel: 128x128 tile, BK=32 double-buffer (33 KB LDS -> 4 blocks/CU),
// counted-vmcnt pipeline (no full drain), XOR-swizzled LDS, c folded into
// MFMA acc init, cheap tanh epilogue. grid (L/128, B, H), block 256.
// ---------------------------------------------------------------------------
#define BK2 32

__global__ __launch_bounds__(256, 4) void score_kernel(
    const u16* __restrict__ Abf, const u16* __restrict__ W1T,
    const float* __restrict__ C, const float* __restrict__ V,
    const float* __restrict__ bV, float* __restrict__ score) {
  int l0 = blockIdx.x * 128;
  int b = blockIdx.y, h = blockIdx.z;
  int tid = threadIdx.x;
  int lane = tid & 63, wid = tid >> 6;
  int wr = wid >> 1, wc = wid & 1;
  int rl = lane & 15;
  int q = lane >> 4;  // 16B k-chunk index within BK2 row

  __shared__ u16 As[2][128 * BK2];  // 8 KB each
  __shared__ u16 Bs[2][128 * BK2];
  __shared__ float redsm[2][128];

  const u16* Fb = Abf + (size_t)b * L_ * DF;
  const u16* Wh = W1T + (size_t)h * U_ * DF;
  const float* Cb = C + (size_t)(b * H_ + h) * U_;
  const float* Vh = V + (size_t)h * U_;

  float part[16];
#pragma unroll
  for (int p = 0; p < 16; ++p) part[p] = 0.f;

  // Per matrix per K-step: 512 16B-chunks; physical chunk (row, ch) holds
  // logical k-chunk ch ^ ((row>>1)&3)  (involution; same XOR on read side).
#define STAGE(buf, kbase)                                                  \
  {                                                                        \
    _Pragma("unroll") for (int i_ = 0; i_ < 2; ++i_) {                     \
      int idx_ = i_ * 256 + tid;                                           \
      int row_ = idx_ >> 2;                                                \
      int ke_ = (((idx_ & 3) ^ ((row_ >> 1) & 3)) << 3);                   \
      load_lds16(Fb + (((size_t)(l0 + row_)) << 9) + (kbase) + ke_,        \
                 &As[buf][idx_ * 8]);                                      \
      load_lds16(Wh + (((size_t)(N0 + row_)) << 9) + (kbase) + ke_,        \
                 &Bs[buf][idx_ * 8]);                                      \
    }                                                                      \
  }

  for (int nc = 0; nc < 4; ++nc) {
    int N0 = nc * 128;
    // per-column h-proj bias and V weight for this n-chunk
    float cu[4], vv[4];
#pragma unroll
    for (int n = 0; n < 4; ++n) {
      int col = N0 + wc * 64 + n * 16 + rl;
      cu[n] = Cb[col];
      vv[n] = Vh[col];
    }
    f32x4 acc[4][4];
#pragma unroll
    for (int m = 0; m < 4; ++m)
#pragma unroll
      for (int n = 0; n < 4; ++n)
#pragma unroll
        for (int j = 0; j < 4; ++j) acc[m][n][j] = cu[n];  // fold +c

    STAGE(0, 0);
    int cur = 0;
    for (int kt = 0; kt < 16; ++kt) {
      if (kt < 15) {
        STAGE(cur ^ 1, (kt + 1) * BK2);
        asm volatile("s_waitcnt vmcnt(4)" ::: "memory");
      } else {
        asm volatile("s_waitcnt vmcnt(0)" ::: "memory");
      }
      __builtin_amdgcn_s_barrier();
      bf16x8 bfr[4];
#pragma unroll
      for (int n = 0; n < 4; ++n) {
        int rB = wc * 64 + n * 16 + rl;
        bfr[n] = *(const bf16x8*)&Bs[cur][(rB << 5) +
                                          ((q ^ ((rB >> 1) & 3)) << 3)];
      }
#pragma unroll
      for (int m = 0; m < 4; ++m) {
        int rA = wr * 64 + m * 16 + rl;
        bf16x8 af = *(const bf16x8*)&As[cur][(rA << 5) +
                                             ((q ^ ((rA >> 1) & 3)) << 3)];
#pragma unroll
        for (int n = 0; n < 4; ++n)
          acc[m][n] = __builtin_amdgcn_mfma_f32_16x16x32_bf16(af, bfr[n],
                                                              acc[m][n], 0, 0,
                                                              0);
      }
      // ensure this wave's LDS reads completed before signaling (rule #18)
      asm volatile("s_waitcnt lgkmcnt(0)" ::: "memory");
      __builtin_amdgcn_s_barrier();
      cur ^= 1;
    }
    // epilogue: tanh, *V, accumulate per-row partials
#pragma unroll
    for (int n = 0; n < 4; ++n)
#pragma unroll
      for (int m = 0; m < 4; ++m)
#pragma unroll
        for (int j = 0; j < 4; ++j)
          part[m * 4 + j] += fast_tanh2(acc[m][n][j]) * vv[n];
  }
#undef STAGE

  // reduce over the 16 cols held per 16-lane group
#pragma unroll
  for (int p = 0; p < 16; ++p) {
    float v = part[p];
    v += __shfl_xor(v, 1, 64);
    v += __shfl_xor(v, 2, 64);
    v += __shfl_xor(v, 4, 64);
    v += __shfl_xor(v, 8, 64);
    part[p] = v;
  }
  __syncthreads();
  if (rl == 0) {
    int rq = lane >> 4;
#pragma unroll
    for (int m = 0; m < 4; ++m)
#pragma unroll
      for (int j = 0; j < 4; ++j)
        redsm[wc][wr * 64 + m * 16 + rq * 4 + j] = part[m * 4 + j];
  }
  __syncthreads();
  if (tid < 128) {
    float s = redsm[0][tid] + redsm[1][tid] + bV[h];
    score[(size_t)(b * H_ + h) * L_ + l0 + tid] = s;
  }
}

// ---------------------------------------------------------------------------
// softmax over L per (b,h), row cached in LDS; writes attn + aw_out [B,L,H,1]
// ---------------------------------------------------------------------------
__global__ __launch_bounds__(256) void softmax_kernel(
    const float* __restrict__ score, float* __restrict__ attn,
    float* __restrict__ aw_out) {
  int bh = blockIdx.x;
  int b = bh / H_, h = bh % H_;
  const float* s = score + (size_t)bh * L_;
  __shared__ float sv[L_];  // 8 KB
  __shared__ float red[256];

  for (int i = threadIdx.x; i < L_ / 4; i += 256)
    ((float4*)sv)[i] = ((const float4*)s)[i];
  __syncthreads();

  float m = -1e30f;
  for (int l = threadIdx.x; l < L_; l += 256) m = fmaxf(m, sv[l]);
  red[threadIdx.x] = m;
  __syncthreads();
  for (int st = 128; st > 0; st >>= 1) {
    if (threadIdx.x < st)
      red[threadIdx.x] = fmaxf(red[threadIdx.x], red[threadIdx.x + st]);
    __syncthreads();
  }
  m = red[0];
  __syncthreads();

  float sum = 0.f;
  for (int l = threadIdx.x; l < L_; l += 256) sum += __expf(sv[l] - m);
  red[threadIdx.x] = sum;
  __syncthreads();
  for (int st = 128; st > 0; st >>= 1) {
    if (threadIdx.x < st) red[threadIdx.x] += red[threadIdx.x + st];
    __syncthreads();
  }
  float inv = 1.f / red[0];

  for (int l = threadIdx.x; l < L_; l += 256) {
    float a = __expf(sv[l] - m) * inv;
    attn[(size_t)bh * L_ + l] = a;
    aw_out[((size_t)b * L_ + l) * H_ + h] = a;
  }
}

// ---------------------------------------------------------------------------
// context split-L: partial[lz][b,h,d] = sum_{l in chunk lz} attn*F
// grid (B, DF/64, 8), block 256. Then combine adds 8 partials.
// ---------------------------------------------------------------------------
__global__ __launch_bounds__(256) void context_part_kernel(
    const float* __restrict__ F, const float* __restrict__ attn,
    float* __restrict__ partial) {
  int b = blockIdx.x;
  int d0 = blockIdx.y * 64;
  int lz = blockIdx.z;
  int td = threadIdx.x & 63;
  int tl = threadIdx.x >> 6;  // 0..3

  __shared__ float as[H_][256];  // 8 KB
  for (int idx = threadIdx.x; idx < H_ * 256; idx += 256)
    as[idx >> 8][idx & 255] =
        attn[((size_t)b * H_ + (idx >> 8)) * L_ + lz * 256 + (idx & 255)];
  __syncthreads();

  float acc[H_] = {};
  for (int l = tl; l < 256; l += 4) {
    float f = F[((size_t)b * L_ + lz * 256 + l) * DF + d0 + td];
#pragma unroll
    for (int h = 0; h < H_; h++) acc[h] += as[h][l] * f;
  }

  __shared__ float red[4][H_][64];  // 8 KB
#pragma unroll
  for (int h = 0; h < H_; h++) red[tl][h][td] = acc[h];
  __syncthreads();
  if (tl == 0) {
#pragma unroll
    for (int h = 0; h < H_; h++) {
      float v = red[0][h][td] + red[1][h][td] + red[2][h][td] + red[3][h][td];
      partial[(size_t)lz * B_ * H_ * DF + ((size_t)b * H_ + h) * DF + d0 + td] =
          v;
    }
  }
}

__global__ __launch_bounds__(256) void context_combine_kernel(
    const float* __restrict__ partial, float* __restrict__ ctx_out) {
  int i = blockIdx.x * 256 + threadIdx.x;  // over B*H*DF
  float s = 0.f;
#pragma unroll
  for (int z = 0; z < 8; z++) s += partial[(size_t)z * B_ * H_ * DF + i];
  ctx_out[i] = s;
}

// ---------------------------------------------------------------------------
extern "C" void kernel_launch(void* const* d_in, const int* in_sizes, int n_in,
                              void* d_out, int out_size, void* d_ws,
                              size_t ws_size, hipStream_t stream) {
  const float* features = (const float*)d_in[0];  // [B,L,Df]
  const float* hidden   = (const float*)d_in[1];  // [B,H,Dh]
  const float* W1       = (const float*)d_in[2];  // [H,Df,U]
  const float* b1       = (const float*)d_in[3];  // [H,U]
  const float* W2       = (const float*)d_in[4];  // [H,Dh,U]
  const float* b2       = (const float*)d_in[5];  // [H,U]
  const float* V        = (const float*)d_in[6];  // [H,U]
  const float* bV       = (const float*)d_in[7];  // [H]

  float* out = (float*)d_out;
  float* ctx_out = out;                 // [B,H,Df]
  float* aw_out  = out + B_ * H_ * DF;  // [B,L,H,1]

  // ws layout (floats): c | score | attn | ctx_partial, then bf16: Abf | W1T
  // hproj partials (8*B*H*U = 524288 f) alias score+attn (524288 f): consumed
  // by hproj_combine before score/attn are written.
  float* c_buf = (float*)d_ws;
  float* score = c_buf + (size_t)B_ * H_ * U_;
  float* attn  = score + (size_t)B_ * H_ * L_;
  float* hpart = score;  // alias (see above)
  float* cpart = attn + (size_t)B_ * H_ * L_;  // 8*B*H*DF = 524288 f
  u16* Abf = (u16*)(cpart + (size_t)8 * B_ * H_ * DF);
  u16* W1T = Abf + (size_t)B_ * L_ * DF;

  convert_kernel<<<16384 + 2048, 256, 0, stream>>>(features, Abf, W1, W1T);
  hproj_part_kernel<<<dim3(H_, U_ / 128, 8), 128, 0, stream>>>(hidden, W2,
                                                               hpart);
  hproj_combine_kernel<<<(B_ * H_ * U_) / 256, 256, 0, stream>>>(hpart, b1, b2,
                                                                 c_buf);
  score_kernel<<<dim3(L_ / 128, B_, H_), 256, 0, stream>>>(Abf, W1T, c_buf, V,
                                                           bV, score);
  softmax_kernel<<<B_ * H_, 256, 0, stream>>>(score, attn, aw_out);
  context_part_kernel<<<dim3(B_, DF / 64, 8), 256, 0, stream>>>(features, attn,
                                                                cpart);
  context_combine_kernel<<<(B_ * H_ * DF) / 256, 256, 0, stream>>>(cpart,
                                                                   ctx_out);
}

// Round 5
// 233.684 us; speedup vs baseline: 8.5642x; 1.4133x over previous
//
#include <hip/hip_runtime.h>
#include <hip/hip_bf16.h>

// Problem dims
#define B_ 16
#define L_ 2048
#define DF 512
#define H_ 8
#define DH 512
#define U_ 512

typedef unsigned short u16;
typedef __attribute__((ext_vector_type(8))) short bf16x8;
typedef __attribute__((ext_vector_type(4))) float f32x4;

__device__ __forceinline__ u16 f2bf(float x) {
  __hip_bfloat16 h = __float2bfloat16(x);
  u16 u;
  __builtin_memcpy(&u, &h, 2);
  return u;
}

__device__ __forceinline__ void load_lds16(const void* g, void* l) {
  __builtin_amdgcn_global_load_lds(
      (const __attribute__((address_space(1))) void*)g,
      (__attribute__((address_space(3))) void*)l, 16, 0, 0);
}

// tanh(x) = 1 - 2/(1+e^{2x}); exact at +-inf, ~1e-6 abs err. ~6 VALU inst.
__device__ __forceinline__ float fast_tanh2(float x) {
  float e = __expf(2.f * x);
  return 1.f - __fdividef(2.f, e + 1.f);
}

// ---------------------------------------------------------------------------
// Merged conversion kernel:
//  blocks [0, 16384): features fp32 -> bf16 [B,L,DF], 4 elems/thread
//  blocks [16384, 18432): W1 [H,DF,U] -> W1T [H,U,DF] bf16 (32x32 transpose)
// ---------------------------------------------------------------------------
__global__ __launch_bounds__(256) void convert_kernel(
    const float* __restrict__ F, u16* __restrict__ Abf,
    const float* __restrict__ W1, u16* __restrict__ W1T) {
  __shared__ float t[32][33];
  if (blockIdx.x < 16384) {
    size_t i = ((size_t)blockIdx.x * 256 + threadIdx.x) * 4;
    float4 v = *(const float4*)(F + i);
    ushort4 o;
    o.x = f2bf(v.x); o.y = f2bf(v.y); o.z = f2bf(v.z); o.w = f2bf(v.w);
    *(ushort4*)(Abf + i) = o;
  } else {
    int bid = blockIdx.x - 16384;
    int d0 = (bid & 15) * 32, u0 = ((bid >> 4) & 15) * 32, h = bid >> 8;
    const float* src = W1 + (size_t)h * DF * U_;
    u16* dst = W1T + (size_t)h * U_ * DF;
#pragma unroll
    for (int i = 0; i < 4; ++i) {
      int idx = threadIdx.x + i * 256;
      int r = idx >> 5, c = idx & 31;
      t[r][c] = src[(size_t)(d0 + r) * U_ + u0 + c];
    }
    __syncthreads();
#pragma unroll
    for (int i = 0; i < 4; ++i) {
      int idx = threadIdx.x + i * 256;
      int r = idx >> 5, c = idx & 31;  // r: u index, c: d index
      dst[(size_t)(u0 + r) * DF + d0 + c] = f2bf(t[c][r]);
    }
  }
}

// ---------------------------------------------------------------------------
// hproj split-d: partial[z,b,h,u] = sum_{d in chunk z} hidden*W2
// ---------------------------------------------------------------------------
__global__ __launch_bounds__(128) void hproj_part_kernel(
    const float* __restrict__ hidden, const float* __restrict__ W2,
    float* __restrict__ partial) {
  int h = blockIdx.x;
  int u = blockIdx.y * 128 + threadIdx.x;
  int d0 = blockIdx.z * 64;
  __shared__ float hs[B_][64];
  for (int idx = threadIdx.x; idx < B_ * 64; idx += 128) {
    int b = idx >> 6, d = idx & 63;
    hs[b][d] = hidden[(size_t)(b * H_ + h) * DH + d0 + d];
  }
  __syncthreads();
  float acc[B_];
#pragma unroll
  for (int b = 0; b < B_; b++) acc[b] = 0.f;
  const float* w2p = W2 + ((size_t)h * DH + d0) * U_ + u;
  for (int d = 0; d < 64; d++) {
    float w = w2p[(size_t)d * U_];
#pragma unroll
    for (int b = 0; b < B_; b++) acc[b] += hs[b][d] * w;
  }
#pragma unroll
  for (int b = 0; b < B_; b++)
    partial[(((size_t)blockIdx.z * B_ + b) * H_ + h) * U_ + u] = acc[b];
}

__global__ __launch_bounds__(256) void hproj_combine_kernel(
    const float* __restrict__ partial, const float* __restrict__ b1,
    const float* __restrict__ b2, float* __restrict__ c) {
  int i = blockIdx.x * 256 + threadIdx.x;  // over B*H*U
  int hu = i & (H_ * U_ - 1);
  float s = b1[hu] + b2[hu];
#pragma unroll
  for (int z = 0; z < 8; z++) s += partial[(size_t)z * B_ * H_ * U_ + i];
  c[i] = s;
}

// ---------------------------------------------------------------------------
// score kernel: 128x128 tile, BK=64 double-buffer (65 KB LDS, 2 blocks/CU,
// reg-limited anyway), counted-vmcnt pipeline (vmcnt(8): one STAGE stays in
// flight across the barrier), XOR-swizzled LDS (conflict-free, r3-verified),
// c folded into MFMA acc init, cheap tanh epilogue.
// grid (L/128, B, H), block 256, launch_bounds (256,2) -- NO spill.
// ---------------------------------------------------------------------------
#define BKS 64

__global__ __launch_bounds__(256, 2) void score_kernel(
    const u16* __restrict__ Abf, const u16* __restrict__ W1T,
    const float* __restrict__ C, const float* __restrict__ V,
    const float* __restrict__ bV, float* __restrict__ score) {
  int l0 = blockIdx.x * 128;
  int b = blockIdx.y, h = blockIdx.z;
  int tid = threadIdx.x;
  int lane = tid & 63, wid = tid >> 6;
  int wr = wid >> 1, wc = wid & 1;
  int rl = lane & 15;
  int khalf = (lane >> 4) << 3;  // bf16 elem offset of this quad's 16B

  __shared__ u16 As[2][128 * BKS];  // 16 KB each
  __shared__ u16 Bs[2][128 * BKS];
  __shared__ float redsm[2][128];

  const u16* Fb = Abf + (size_t)b * L_ * DF;
  const u16* Wh = W1T + (size_t)h * U_ * DF;
  const float* Cb = C + (size_t)(b * H_ + h) * U_;
  const float* Vh = V + (size_t)h * U_;

  float part[16];
#pragma unroll
  for (int p = 0; p < 16; ++p) part[p] = 0.f;

  // Per matrix per K-step: 1024 16B-chunks; physical chunk (row, ch) holds
  // logical k-chunk ch ^ (row&7)  (involution; same XOR on the read side).
#define STAGE(buf, kbase)                                                  \
  {                                                                        \
    _Pragma("unroll") for (int i_ = 0; i_ < 4; ++i_) {                     \
      int idx_ = i_ * 256 + tid;                                           \
      int row_ = idx_ >> 3;                                                \
      int ke_ = ((idx_ & 7) ^ (row_ & 7)) << 3;                            \
      load_lds16(Fb + (((size_t)(l0 + row_)) << 9) + (kbase) + ke_,        \
                 &As[buf][idx_ * 8]);                                      \
      load_lds16(Wh + (((size_t)(N0 + row_)) << 9) + (kbase) + ke_,        \
                 &Bs[buf][idx_ * 8]);                                      \
    }                                                                      \
  }

  for (int nc = 0; nc < 4; ++nc) {
    int N0 = nc * 128;
    // per-column h-proj bias and V weight for this n-chunk
    float cu[4], vv[4];
#pragma unroll
    for (int n = 0; n < 4; ++n) {
      int col = N0 + wc * 64 + n * 16 + rl;
      cu[n] = Cb[col];
      vv[n] = Vh[col];
    }
    f32x4 acc[4][4];
#pragma unroll
    for (int m = 0; m < 4; ++m)
#pragma unroll
      for (int n = 0; n < 4; ++n)
#pragma unroll
        for (int j = 0; j < 4; ++j) acc[m][n][j] = cu[n];  // fold +c

    STAGE(0, 0);
    int cur = 0;
    for (int kt = 0; kt < 8; ++kt) {
      if (kt < 7) {
        STAGE(cur ^ 1, (kt + 1) * BKS);
        asm volatile("s_waitcnt vmcnt(8)" ::: "memory");
      } else {
        asm volatile("s_waitcnt vmcnt(0)" ::: "memory");
      }
      __builtin_amdgcn_s_barrier();
#pragma unroll
      for (int s = 0; s < 2; ++s) {
        bf16x8 bfr[4];
#pragma unroll
        for (int n = 0; n < 4; ++n) {
          int rB = wc * 64 + n * 16 + rl;
          bfr[n] = *(const bf16x8*)&Bs[cur][(rB << 6) +
                                            ((s * 32 + khalf) ^ ((rB & 7) << 3))];
        }
#pragma unroll
        for (int m = 0; m < 4; ++m) {
          int rA = wr * 64 + m * 16 + rl;
          bf16x8 af = *(const bf16x8*)&As[cur][(rA << 6) +
                                               ((s * 32 + khalf) ^
                                                ((rA & 7) << 3))];
#pragma unroll
          for (int n = 0; n < 4; ++n)
            acc[m][n] = __builtin_amdgcn_mfma_f32_16x16x32_bf16(
                af, bfr[n], acc[m][n], 0, 0, 0);
        }
      }
      // this wave's LDS reads must complete before signaling next overwrite
      asm volatile("s_waitcnt lgkmcnt(0)" ::: "memory");
      __builtin_amdgcn_s_barrier();
      cur ^= 1;
    }
    // epilogue: tanh, *V, accumulate per-row partials
#pragma unroll
    for (int n = 0; n < 4; ++n)
#pragma unroll
      for (int m = 0; m < 4; ++m)
#pragma unroll
        for (int j = 0; j < 4; ++j)
          part[m * 4 + j] += fast_tanh2(acc[m][n][j]) * vv[n];
  }
#undef STAGE

  // reduce over the 16 cols held per 16-lane group
#pragma unroll
  for (int p = 0; p < 16; ++p) {
    float v = part[p];
    v += __shfl_xor(v, 1, 64);
    v += __shfl_xor(v, 2, 64);
    v += __shfl_xor(v, 4, 64);
    v += __shfl_xor(v, 8, 64);
    part[p] = v;
  }
  __syncthreads();
  if (rl == 0) {
    int rq = lane >> 4;
#pragma unroll
    for (int m = 0; m < 4; ++m)
#pragma unroll
      for (int j = 0; j < 4; ++j)
        redsm[wc][wr * 64 + m * 16 + rq * 4 + j] = part[m * 4 + j];
  }
  __syncthreads();
  if (tid < 128) {
    float s = redsm[0][tid] + redsm[1][tid] + bV[h];
    score[(size_t)(b * H_ + h) * L_ + l0 + tid] = s;
  }
}

// ---------------------------------------------------------------------------
// softmax over L per (b,h), row cached in LDS; writes attn + aw_out [B,L,H,1]
// ---------------------------------------------------------------------------
__global__ __launch_bounds__(256) void softmax_kernel(
    const float* __restrict__ score, float* __restrict__ attn,
    float* __restrict__ aw_out) {
  int bh = blockIdx.x;
  int b = bh / H_, h = bh % H_;
  const float* s = score + (size_t)bh * L_;
  __shared__ float sv[L_];  // 8 KB
  __shared__ float red[256];

  for (int i = threadIdx.x; i < L_ / 4; i += 256)
    ((float4*)sv)[i] = ((const float4*)s)[i];
  __syncthreads();

  float m = -1e30f;
  for (int l = threadIdx.x; l < L_; l += 256) m = fmaxf(m, sv[l]);
  red[threadIdx.x] = m;
  __syncthreads();
  for (int st = 128; st > 0; st >>= 1) {
    if (threadIdx.x < st)
      red[threadIdx.x] = fmaxf(red[threadIdx.x], red[threadIdx.x + st]);
    __syncthreads();
  }
  m = red[0];
  __syncthreads();

  float sum = 0.f;
  for (int l = threadIdx.x; l < L_; l += 256) sum += __expf(sv[l] - m);
  red[threadIdx.x] = sum;
  __syncthreads();
  for (int st = 128; st > 0; st >>= 1) {
    if (threadIdx.x < st) red[threadIdx.x] += red[threadIdx.x + st];
    __syncthreads();
  }
  float inv = 1.f / red[0];

  for (int l = threadIdx.x; l < L_; l += 256) {
    float a = __expf(sv[l] - m) * inv;
    attn[(size_t)bh * L_ + l] = a;
    aw_out[((size_t)b * L_ + l) * H_ + h] = a;
  }
}

// ---------------------------------------------------------------------------
// context split-L: partial[lz][b,h,d] = sum_{l in chunk lz} attn*F
// grid (B, DF/64, 8), block 256. Then combine adds 8 partials.
// ---------------------------------------------------------------------------
__global__ __launch_bounds__(256) void context_part_kernel(
    const float* __restrict__ F, const float* __restrict__ attn,
    float* __restrict__ partial) {
  int b = blockIdx.x;
  int d0 = blockIdx.y * 64;
  int lz = blockIdx.z;
  int td = threadIdx.x & 63;
  int tl = threadIdx.x >> 6;  // 0..3

  __shared__ float as[H_][256];  // 8 KB
  for (int idx = threadIdx.x; idx < H_ * 256; idx += 256)
    as[idx >> 8][idx & 255] =
        attn[((size_t)b * H_ + (idx >> 8)) * L_ + lz * 256 + (idx & 255)];
  __syncthreads();

  float acc[H_] = {};
  for (int l = tl; l < 256; l += 4) {
    float f = F[((size_t)b * L_ + lz * 256 + l) * DF + d0 + td];
#pragma unroll
    for (int h = 0; h < H_; h++) acc[h] += as[h][l] * f;
  }

  __shared__ float red[4][H_][64];  // 8 KB
#pragma unroll
  for (int h = 0; h < H_; h++) red[tl][h][td] = acc[h];
  __syncthreads();
  if (tl == 0) {
#pragma unroll
    for (int h = 0; h < H_; h++) {
      float v = red[0][h][td] + red[1][h][td] + red[2][h][td] + red[3][h][td];
      partial[(size_t)lz * B_ * H_ * DF + ((size_t)b * H_ + h) * DF + d0 + td] =
          v;
    }
  }
}

__global__ __launch_bounds__(256) void context_combine_kernel(
    const float* __restrict__ partial, float* __restrict__ ctx_out) {
  int i = blockIdx.x * 256 + threadIdx.x;  // over B*H*DF
  float s = 0.f;
#pragma unroll
  for (int z = 0; z < 8; z++) s += partial[(size_t)z * B_ * H_ * DF + i];
  ctx_out[i] = s;
}

// ---------------------------------------------------------------------------
extern "C" void kernel_launch(void* const* d_in, const int* in_sizes, int n_in,
                              void* d_out, int out_size, void* d_ws,
                              size_t ws_size, hipStream_t stream) {
  const float* features = (const float*)d_in[0];  // [B,L,Df]
  const float* hidden   = (const float*)d_in[1];  // [B,H,Dh]
  const float* W1       = (const float*)d_in[2];  // [H,Df,U]
  const float* b1       = (const float*)d_in[3];  // [H,U]
  const float* W2       = (const float*)d_in[4];  // [H,Dh,U]
  const float* b2       = (const float*)d_in[5];  // [H,U]
  const float* V        = (const float*)d_in[6];  // [H,U]
  const float* bV       = (const float*)d_in[7];  // [H]

  float* out = (float*)d_out;
  float* ctx_out = out;                 // [B,H,Df]
  float* aw_out  = out + B_ * H_ * DF;  // [B,L,H,1]

  // ws layout (floats): c | score | attn | ctx_partial, then bf16: Abf | W1T
  // hproj partials (8*B*H*U = 524288 f) alias score+attn (524288 f): consumed
  // by hproj_combine before score/attn are written.
  float* c_buf = (float*)d_ws;
  float* score = c_buf + (size_t)B_ * H_ * U_;
  float* attn  = score + (size_t)B_ * H_ * L_;
  float* hpart = score;  // alias (see above)
  float* cpart = attn + (size_t)B_ * H_ * L_;  // 8*B*H*DF = 524288 f
  u16* Abf = (u16*)(cpart + (size_t)8 * B_ * H_ * DF);
  u16* W1T = Abf + (size_t)B_ * L_ * DF;

  convert_kernel<<<16384 + 2048, 256, 0, stream>>>(features, Abf, W1, W1T);
  hproj_part_kernel<<<dim3(H_, U_ / 128, 8), 128, 0, stream>>>(hidden, W2,
                                                               hpart);
  hproj_combine_kernel<<<(B_ * H_ * U_) / 256, 256, 0, stream>>>(hpart, b1, b2,
                                                                 c_buf);
  score_kernel<<<dim3(L_ / 128, B_, H_), 256, 0, stream>>>(Abf, W1T, c_buf, V,
                                                           bV, score);
  softmax_kernel<<<B_ * H_, 256, 0, stream>>>(score, attn, aw_out);
  context_part_kernel<<<dim3(B_, DF / 64, 8), 256, 0, stream>>>(features, attn,
                                                                cpart);
  context_combine_kernel<<<(B_ * H_ * DF) / 256, 256, 0, stream>>>(cpart,
                                                                   ctx_out);
}